// Round 1
// baseline (786.244 us; speedup 1.0000x reference)
//
#include <hip/hip_runtime.h>

#define NBRS 200
#define BATCH 2048
#define FEW 5
#define DMODEL 256
#define DINNER 512
#define LHID 512
#define GDIM 2048   // 4*LHID
#define EDIM 128
#define LNEPS 1e-3f

__device__ __forceinline__ float sigmoidf_(float x) { return 1.f / (1.f + expf(-x)); }

// ---------------------------------------------------------------------------
// Gather + sum of 200 neighbor embedding pairs: S[n, 0:128] = sum_k emb[conn[n,k,0]],
// S[n,128:256] = sum_k emb[conn[n,k,1]]
// ---------------------------------------------------------------------------
__global__ __launch_bounds__(256) void nbr_sum(const int* __restrict__ conn,
                                               const float* __restrict__ emb,
                                               float* __restrict__ S) {
    int row = blockIdx.x;
    __shared__ int idx[NBRS * 2];
    int t = threadIdx.x;
    for (int i = t; i < NBRS * 2; i += 256) idx[i] = conn[row * NBRS * 2 + i];
    __syncthreads();
    int sel = t >> 7;      // 0 = rel, 1 = ent
    int d = t & 127;
    float acc = 0.f;
#pragma unroll 4
    for (int k = 0; k < NBRS; ++k) {
        int e = idx[k * 2 + sel];
        acc += emb[(size_t)e * EDIM + d];
    }
    S[(size_t)row * 256 + t] = acc;
}

// gcn_w (128,256) -> gcn_wT (256,128)
__global__ void transpose_gcnw(const float* __restrict__ W, float* __restrict__ WT) {
    int i = blockIdx.x * 256 + threadIdx.x;  // 128*256
    int d = i >> 8, c = i & 255;
    WT[c * 128 + d] = W[i];
}

// out[row, off+d] = tanh((S[row]·gcn_wT[:,d] + 200*bias[d]) / deg[row])
__global__ __launch_bounds__(128) void gcn_kernel(const float* __restrict__ S,
                                                  const float* __restrict__ deg,
                                                  const float* __restrict__ WT,
                                                  const float* __restrict__ bias,
                                                  float* __restrict__ out, int off) {
    int row = blockIdx.x;
    int d = threadIdx.x;  // 128
    __shared__ float sS[256];
    sS[d] = S[(size_t)row * 256 + d];
    sS[d + 128] = S[(size_t)row * 256 + 128 + d];
    __syncthreads();
    float acc = 0.f;
#pragma unroll 8
    for (int c = 0; c < 256; ++c) acc = fmaf(sS[c], WT[c * 128 + d], acc);
    float v = (acc + 200.f * bias[d]) / deg[row];
    out[(size_t)row * 256 + off + d] = tanhf(v);
}

// ---------------------------------------------------------------------------
// Generic fp32 NT GEMM: C[m,n] = sum_k A[m,k]*B[n,k]  (+bias[n]) (+addm[m,n]) (relu)
// BM=BN=128, BK=16, 256 threads, 8x8 micro-tile per thread.
// ---------------------------------------------------------------------------
#define BM 128
#define BN 128
#define BK 16

template <int RELU, int BIAS, int ADD>
__global__ __launch_bounds__(256) void gemm_nt(const float* __restrict__ A, int lda,
                                               const float* __restrict__ B, int ldb,
                                               float* __restrict__ C, int ldc,
                                               const float* __restrict__ bias,
                                               const float* __restrict__ addm, int ldadd,
                                               int M, int N, int K) {
    __shared__ float As[BK][BM];
    __shared__ float Bs[BK][BN];
    int tx = threadIdx.x & 15;
    int ty = threadIdx.x >> 4;
    int m0 = blockIdx.y * BM;
    int n0 = blockIdx.x * BN;

    float acc[8][8];
#pragma unroll
    for (int i = 0; i < 8; i++)
#pragma unroll
        for (int j = 0; j < 8; j++) acc[i][j] = 0.f;

    int lr = threadIdx.x >> 1;       // 0..127
    int lk = (threadIdx.x & 1) * 8;  // 0 or 8

    for (int k0 = 0; k0 < K; k0 += BK) {
        float4 v0, v1;
        int gm = m0 + lr;
        if (gm < M) {
            const float* p = A + (size_t)gm * lda + k0 + lk;
            v0 = *(const float4*)p;
            v1 = *(const float4*)(p + 4);
        } else {
            v0 = make_float4(0, 0, 0, 0);
            v1 = v0;
        }
        As[lk + 0][lr] = v0.x; As[lk + 1][lr] = v0.y; As[lk + 2][lr] = v0.z; As[lk + 3][lr] = v0.w;
        As[lk + 4][lr] = v1.x; As[lk + 5][lr] = v1.y; As[lk + 6][lr] = v1.z; As[lk + 7][lr] = v1.w;
        int gn = n0 + lr;
        if (gn < N) {
            const float* p = B + (size_t)gn * ldb + k0 + lk;
            v0 = *(const float4*)p;
            v1 = *(const float4*)(p + 4);
        } else {
            v0 = make_float4(0, 0, 0, 0);
            v1 = v0;
        }
        Bs[lk + 0][lr] = v0.x; Bs[lk + 1][lr] = v0.y; Bs[lk + 2][lr] = v0.z; Bs[lk + 3][lr] = v0.w;
        Bs[lk + 4][lr] = v1.x; Bs[lk + 5][lr] = v1.y; Bs[lk + 6][lr] = v1.z; Bs[lk + 7][lr] = v1.w;
        __syncthreads();
#pragma unroll
        for (int kk = 0; kk < BK; kk++) {
            const float4 a0 = *(const float4*)&As[kk][ty * 4];
            const float4 a1 = *(const float4*)&As[kk][64 + ty * 4];
            const float4 b0 = *(const float4*)&Bs[kk][tx * 4];
            const float4 b1 = *(const float4*)&Bs[kk][64 + tx * 4];
            float a[8] = {a0.x, a0.y, a0.z, a0.w, a1.x, a1.y, a1.z, a1.w};
            float b[8] = {b0.x, b0.y, b0.z, b0.w, b1.x, b1.y, b1.z, b1.w};
#pragma unroll
            for (int i = 0; i < 8; i++)
#pragma unroll
                for (int j = 0; j < 8; j++) acc[i][j] = fmaf(a[i], b[j], acc[i][j]);
        }
        __syncthreads();
    }

#pragma unroll
    for (int i = 0; i < 8; i++) {
        int gm = m0 + ((i < 4) ? (ty * 4 + i) : (64 + ty * 4 + (i - 4)));
        if (gm >= M) continue;
#pragma unroll
        for (int jh = 0; jh < 2; jh++) {
            int gn = n0 + jh * 64 + tx * 4;
            if (gn >= N) continue;
            float r0 = acc[i][jh * 4 + 0], r1 = acc[i][jh * 4 + 1];
            float r2 = acc[i][jh * 4 + 2], r3 = acc[i][jh * 4 + 3];
            if (BIAS) {
                const float4 bv = *(const float4*)&bias[gn];
                r0 += bv.x; r1 += bv.y; r2 += bv.z; r3 += bv.w;
            }
            if (ADD) {
                const float4 av = *(const float4*)&addm[(size_t)gm * ldadd + gn];
                r0 += av.x; r1 += av.y; r2 += av.z; r3 += av.w;
            }
            if (RELU) {
                r0 = fmaxf(r0, 0.f); r1 = fmaxf(r1, 0.f);
                r2 = fmaxf(r2, 0.f); r3 = fmaxf(r3, 0.f);
            }
            float4 rv = make_float4(r0, r1, r2, r3);
            *(float4*)&C[(size_t)gm * ldc + gn] = rv;
        }
    }
}

// LayerNorm with ddof=1 std, one wave per 256-elem row
__global__ __launch_bounds__(256) void ln_kernel(const float* __restrict__ X,
                                                 const float* __restrict__ la,
                                                 const float* __restrict__ lb,
                                                 float* __restrict__ Y, int n) {
    int row = blockIdx.x * 4 + (threadIdx.x >> 6);
    int lane = threadIdx.x & 63;
    if (row >= n) return;
    float4 x = *(const float4*)(X + (size_t)row * 256 + lane * 4);
    float s = x.x + x.y + x.z + x.w;
#pragma unroll
    for (int o = 32; o; o >>= 1) s += __shfl_xor(s, o);
    float mu = s * (1.f / 256.f);
    float d0 = x.x - mu, d1 = x.y - mu, d2 = x.z - mu, d3 = x.w - mu;
    float q = d0 * d0 + d1 * d1 + d2 * d2 + d3 * d3;
#pragma unroll
    for (int o = 32; o; o >>= 1) q += __shfl_xor(q, o);
    float sigma = sqrtf(q * (1.f / 255.f));  // ddof=1
    float inv = 1.f / (sigma + LNEPS);
    float4 a = *(const float4*)(la + lane * 4);
    float4 b = *(const float4*)(lb + lane * 4);
    float4 y = make_float4(d0 * inv * a.x + b.x, d1 * inv * a.y + b.y,
                           d2 * inv * a.z + b.z, d3 * inv * a.w + b.w);
    *(float4*)(Y + (size_t)row * 256 + lane * 4) = y;
}

__global__ void mean5(const float* __restrict__ sg, float* __restrict__ s) {
    int d = threadIdx.x;  // 256
    float v = 0.f;
#pragma unroll
    for (int r = 0; r < FEW; r++) v += sg[r * 256 + d];
    s[d] = v * (1.f / FEW);
}

// svec[j] = s · w_hh[j, 256:512]; bsum[j] = b_ih[j] + b_hh[j]
__global__ __launch_bounds__(256) void svec_bsum(const float* __restrict__ s,
                                                 const float* __restrict__ w_hh,
                                                 const float* __restrict__ b_ih,
                                                 const float* __restrict__ b_hh,
                                                 float* __restrict__ svec,
                                                 float* __restrict__ bsum) {
    int j = blockIdx.x * 4 + (threadIdx.x >> 6);
    int lane = threadIdx.x & 63;
    const float* w = w_hh + (size_t)j * LHID + 256;
    float4 v = ((const float4*)w)[lane];
    float4 sv = ((const float4*)s)[lane];
    float p = v.x * sv.x + v.y * sv.y + v.z * sv.z + v.w * sv.w;
#pragma unroll
    for (int o = 32; o; o >>= 1) p += __shfl_down(p, o);
    if (lane == 0) {
        svec[j] = p;
        bsum[j] = b_ih[j] + b_hh[j];
    }
}

// LSTM gate nonlinearity. G rows are 2048 wide: [i | f | g | o] blocks of 512.
template <int FIRST>
__global__ __launch_bounds__(256) void gates_kernel(const float* __restrict__ G,
                                                    const float* __restrict__ qg,
                                                    float* __restrict__ Cst,
                                                    float* __restrict__ H) {
    int idx = blockIdx.x * 256 + threadIdx.x;  // BATCH*512
    int b = idx >> 9, j = idx & 511;
    const float* g = G + (size_t)b * GDIM;
    float gi = g[j], gf = g[512 + j], gg = g[1024 + j], go = g[1536 + j];
    float cn;
    if (FIRST)
        cn = sigmoidf_(gi) * tanhf(gg);  // c_prev = 0
    else
        cn = sigmoidf_(gf) * Cst[idx] + sigmoidf_(gi) * tanhf(gg);
    Cst[idx] = cn;
    if (j < 256) H[(size_t)b * 256 + j] = qg[(size_t)b * 256 + j] + sigmoidf_(go) * tanhf(cn);
}

__global__ __launch_bounds__(256) void scores_kernel(const float* __restrict__ H,
                                                     const float* __restrict__ s,
                                                     float* __restrict__ out) {
    int row = blockIdx.x * 4 + (threadIdx.x >> 6);
    int lane = threadIdx.x & 63;
    float4 h = *(const float4*)(H + (size_t)row * 256 + lane * 4);
    float4 sv = *(const float4*)(s + lane * 4);
    float p = h.x * sv.x + h.y * sv.y + h.z * sv.z + h.w * sv.w;
#pragma unroll
    for (int o = 32; o; o >>= 1) p += __shfl_down(p, o);
    if (lane == 0) out[row] = p;
}

extern "C" void kernel_launch(void* const* d_in, const int* in_sizes, int n_in,
                              void* d_out, int out_size, void* d_ws, size_t ws_size,
                              hipStream_t stream) {
    const int* qlc = (const int*)d_in[0];
    const float* qld = (const float*)d_in[1];
    const int* qrc = (const int*)d_in[2];
    const float* qrd = (const float*)d_in[3];
    const int* slc = (const int*)d_in[4];
    const float* sld = (const float*)d_in[5];
    const int* src_ = (const int*)d_in[6];
    const float* srd = (const float*)d_in[7];
    const float* emb = (const float*)d_in[8];
    const float* gcn_w = (const float*)d_in[9];
    const float* gcn_b = (const float*)d_in[10];
    const float* w1 = (const float*)d_in[11];
    const float* b1 = (const float*)d_in[12];
    const float* w2 = (const float*)d_in[13];
    const float* b2 = (const float*)d_in[14];
    const float* lna = (const float*)d_in[15];
    const float* lnb = (const float*)d_in[16];
    const float* w_ih = (const float*)d_in[17];
    const float* w_hh = (const float*)d_in[18];
    const float* b_ih = (const float*)d_in[19];
    const float* b_hh = (const float*)d_in[20];
    float* out = (float*)d_out;

    float* ws = (float*)d_ws;
    size_t off = 0;
    auto alloc = [&](size_t n) { float* p = ws + off; off += n; return p; };
    float* gcn_wT = alloc(256 * 128);
    float* S_ql = alloc((size_t)BATCH * 256);
    float* S_qr = alloc((size_t)BATCH * 256);
    float* S_sl = alloc(FEW * 256);
    float* S_sr = alloc(FEW * 256);
    float* qn = alloc((size_t)BATCH * 256);
    float* sn = alloc(FEW * 256);
    float* H1q = alloc((size_t)BATCH * 512);
    float* H1s = alloc(FEW * 512);
    float* preq = alloc((size_t)BATCH * 256);
    float* pres = alloc(FEW * 256);
    float* qg = alloc((size_t)BATCH * 256);
    float* sg = alloc(FEW * 256);
    float* svec = alloc(2048);
    float* bsum = alloc(2048);
    float* sbar = alloc(256);
    float* base = alloc((size_t)BATCH * GDIM);
    float* Gbuf = alloc((size_t)BATCH * GDIM);
    float* Cst = alloc((size_t)BATCH * LHID);
    float* Hst = alloc((size_t)BATCH * 256);
    (void)ws_size;

    transpose_gcnw<<<128, 256, 0, stream>>>(gcn_w, gcn_wT);
    nbr_sum<<<BATCH, 256, 0, stream>>>(qlc, emb, S_ql);
    nbr_sum<<<BATCH, 256, 0, stream>>>(qrc, emb, S_qr);
    nbr_sum<<<FEW, 256, 0, stream>>>(slc, emb, S_sl);
    nbr_sum<<<FEW, 256, 0, stream>>>(src_, emb, S_sr);

    gcn_kernel<<<BATCH, 128, 0, stream>>>(S_ql, qld, gcn_wT, gcn_b, qn, 0);
    gcn_kernel<<<BATCH, 128, 0, stream>>>(S_qr, qrd, gcn_wT, gcn_b, qn, 128);
    gcn_kernel<<<FEW, 128, 0, stream>>>(S_sl, sld, gcn_wT, gcn_b, sn, 0);
    gcn_kernel<<<FEW, 128, 0, stream>>>(S_sr, srd, gcn_wT, gcn_b, sn, 128);

    // support encoder: H1 = relu(X W1^T + b1); pre = H1 W2^T + b2 + X; LN
    gemm_nt<1, 1, 0><<<dim3(DINNER / BN, BATCH / BM), 256, 0, stream>>>(
        qn, 256, w1, 256, H1q, 512, b1, nullptr, 0, BATCH, DINNER, 256);
    gemm_nt<1, 1, 0><<<dim3(DINNER / BN, 1), 256, 0, stream>>>(
        sn, 256, w1, 256, H1s, 512, b1, nullptr, 0, FEW, DINNER, 256);
    gemm_nt<0, 1, 1><<<dim3(DMODEL / BN, BATCH / BM), 256, 0, stream>>>(
        H1q, 512, w2, 512, preq, 256, b2, qn, 256, BATCH, DMODEL, 512);
    gemm_nt<0, 1, 1><<<dim3(DMODEL / BN, 1), 256, 0, stream>>>(
        H1s, 512, w2, 512, pres, 256, b2, sn, 256, FEW, DMODEL, 512);
    ln_kernel<<<BATCH / 4, 256, 0, stream>>>(preq, lna, lnb, qg, BATCH);
    ln_kernel<<<2, 256, 0, stream>>>(pres, lna, lnb, sg, FEW);
    mean5<<<1, 256, 0, stream>>>(sg, sbar);

    svec_bsum<<<GDIM / 4, 256, 0, stream>>>(sbar, w_hh, b_ih, b_hh, svec, bsum);

    // base = qg @ w_ih^T + (b_ih + b_hh)
    gemm_nt<0, 1, 0><<<dim3(GDIM / BN, BATCH / BM), 256, 0, stream>>>(
        qg, 256, w_ih, 256, base, GDIM, bsum, nullptr, 0, BATCH, GDIM, 256);

    // step 1: h_r = 0 -> gates directly from base
    gates_kernel<1><<<BATCH * LHID / 256, 256, 0, stream>>>(base, qg, Cst, Hst);
    // steps 2..4: G = base + svec + H @ w_hh[:, :256]^T
    for (int s = 2; s <= 4; s++) {
        gemm_nt<0, 1, 1><<<dim3(GDIM / BN, BATCH / BM), 256, 0, stream>>>(
            Hst, 256, w_hh, 512, Gbuf, GDIM, svec, base, GDIM, BATCH, GDIM, 256);
        gates_kernel<0><<<BATCH * LHID / 256, 256, 0, stream>>>(Gbuf, qg, Cst, Hst);
    }

    scores_kernel<<<BATCH / 4, 256, 0, stream>>>(Hst, sbar, out);
}